// Round 1
// baseline (716.448 us; speedup 1.0000x reference)
//
#include <hip/hip_runtime.h>
#include <hip/hip_bf16.h>
#include <stdint.h>

#define NROWS 4096
#define DIM   1024
#define NCLS  64

#define BM 64
#define BN 64
#define BK 32
#define CHUNK_TILES 4           // 4 j-tiles of 64 cols per block = 256-col chunk
#define CHUNKS 16               // 4096 / 256

constexpr float TEMP_INV = 1.0f / 0.07f;

// ---------------- kernel A: bce row-sums, entropy weights, label bitmasks ----
// one wave (64 lanes) per row; lane == class (C == 64 == wavefront)
__global__ void prep_kernel(const float* __restrict__ logits,
                            const int* __restrict__ labels,
                            uint64_t* __restrict__ maskout,
                            float* __restrict__ wout,
                            float* __restrict__ bceout) {
    const int row  = blockIdx.x * 4 + (threadIdx.x >> 6);
    const int lane = threadIdx.x & 63;
    const float l = logits[row * NCLS + lane];
    const int   y = labels[row * NCLS + lane];
    const float yf = (float)y;

    float bce = fmaxf(l, 0.0f) - l * yf + log1pf(expf(-fabsf(l)));
    const float pr = 1.0f / (1.0f + expf(-l));
    const float ent = -(pr * logf(pr + 1e-8f) + (1.0f - pr) * logf(1.0f - pr + 1e-8f));
    float entw = ent * yf;
    float ycnt = yf;

    #pragma unroll
    for (int off = 32; off; off >>= 1) {
        bce  += __shfl_down(bce, off);
        entw += __shfl_down(entw, off);
        ycnt += __shfl_down(ycnt, off);
    }
    const uint64_t m = __ballot(y != 0);
    if (lane == 0) {
        maskout[row] = m;
        wout[row]    = entw / (ycnt + 1e-8f);
        bceout[row]  = bce;
    }
}

// ---------------- kernel B: tiled emb@emb^T with online (m,p,s) per row ------
__global__ __launch_bounds__(256, 4)
void sim_kernel(const float* __restrict__ emb,
                const uint64_t* __restrict__ mask,
                float4* __restrict__ partial) {
    __shared__ float As[BK][BM];
    __shared__ float Bs[BK][BM];

    const int tid = threadIdx.x;
    const int tx = tid & 15;       // 0..15 -> cols
    const int ty = tid >> 4;       // 0..15 -> rows
    const int row0  = blockIdx.y * BM;
    const int chunk = blockIdx.x;
    const int col0  = chunk * (BN * CHUNK_TILES);

    const int lrow = tid >> 3;     // 0..31 for staging loads
    const int lq   = tid & 7;      // k-quad 0..7

    int gi[4];
    uint64_t rmask[4];
    #pragma unroll
    for (int r = 0; r < 4; ++r) {
        gi[r] = row0 + ty * 4 + r;
        rmask[r] = mask[gi[r]];
    }

    float m_[4], p_[4], s_[4];
    #pragma unroll
    for (int r = 0; r < 4; ++r) { m_[r] = -1e30f; p_[r] = 0.0f; s_[r] = 0.0f; }

    for (int jt = 0; jt < CHUNK_TILES; ++jt) {
        const int jcol0 = col0 + jt * BN;

        float acc[4][4];
        #pragma unroll
        for (int r = 0; r < 4; ++r)
            #pragma unroll
            for (int c = 0; c < 4; ++c) acc[r][c] = 0.0f;

        for (int kb = 0; kb < DIM; kb += BK) {
            const float4 a0 = *reinterpret_cast<const float4*>(&emb[(size_t)(row0 + lrow) * DIM + kb + lq * 4]);
            const float4 a1 = *reinterpret_cast<const float4*>(&emb[(size_t)(row0 + lrow + 32) * DIM + kb + lq * 4]);
            const float4 b0 = *reinterpret_cast<const float4*>(&emb[(size_t)(jcol0 + lrow) * DIM + kb + lq * 4]);
            const float4 b1 = *reinterpret_cast<const float4*>(&emb[(size_t)(jcol0 + lrow + 32) * DIM + kb + lq * 4]);
            __syncthreads();   // previous iteration's reads done
            As[lq * 4 + 0][lrow] = a0.x;  As[lq * 4 + 1][lrow] = a0.y;
            As[lq * 4 + 2][lrow] = a0.z;  As[lq * 4 + 3][lrow] = a0.w;
            As[lq * 4 + 0][lrow + 32] = a1.x;  As[lq * 4 + 1][lrow + 32] = a1.y;
            As[lq * 4 + 2][lrow + 32] = a1.z;  As[lq * 4 + 3][lrow + 32] = a1.w;
            Bs[lq * 4 + 0][lrow] = b0.x;  Bs[lq * 4 + 1][lrow] = b0.y;
            Bs[lq * 4 + 2][lrow] = b0.z;  Bs[lq * 4 + 3][lrow] = b0.w;
            Bs[lq * 4 + 0][lrow + 32] = b1.x;  Bs[lq * 4 + 1][lrow + 32] = b1.y;
            Bs[lq * 4 + 2][lrow + 32] = b1.z;  Bs[lq * 4 + 3][lrow + 32] = b1.w;
            __syncthreads();

            #pragma unroll 8
            for (int kk = 0; kk < BK; ++kk) {
                const float4 av = *reinterpret_cast<const float4*>(&As[kk][ty * 4]);
                const float4 bv = *reinterpret_cast<const float4*>(&Bs[kk][tx * 4]);
                const float a_[4] = {av.x, av.y, av.z, av.w};
                const float b_[4] = {bv.x, bv.y, bv.z, bv.w};
                #pragma unroll
                for (int r = 0; r < 4; ++r)
                    #pragma unroll
                    for (int c = 0; c < 4; ++c)
                        acc[r][c] = fmaf(a_[r], b_[c], acc[r][c]);
            }
        }

        // ---- online softmax update for this 4x4 group ----
        int gj[4];
        uint64_t cmask[4];
        #pragma unroll
        for (int c = 0; c < 4; ++c) {
            gj[c] = jcol0 + tx * 4 + c;
            cmask[c] = mask[gj[c]];
        }
        #pragma unroll
        for (int r = 0; r < 4; ++r) {
            float sim[4];
            bool od[4], pos[4];
            float tmax = -1e30f;
            #pragma unroll
            for (int c = 0; c < 4; ++c) {
                sim[c] = acc[r][c] * TEMP_INV;
                od[c]  = (gj[c] != gi[r]);
                pos[c] = od[c] && ((rmask[r] & cmask[c]) != 0ull);
                if (od[c]) tmax = fmaxf(tmax, sim[c]);
            }
            const float newm = fmaxf(m_[r], tmax);
            const float scale = __expf(m_[r] - newm);
            float ps = 0.0f, ss = 0.0f;
            #pragma unroll
            for (int c = 0; c < 4; ++c) {
                if (od[c]) {
                    const float e = __expf(sim[c] - newm);
                    ss += e;
                    if (pos[c]) ps += e;
                }
            }
            p_[r] = p_[r] * scale + ps;
            s_[r] = s_[r] * scale + ss;
            m_[r] = newm;
        }
    }

    // ---- merge across the 16 tx lanes (same ty -> same rows) ----
    #pragma unroll
    for (int off = 1; off < 16; off <<= 1) {
        #pragma unroll
        for (int r = 0; r < 4; ++r) {
            const float om = __shfl_xor(m_[r], off);
            const float op = __shfl_xor(p_[r], off);
            const float os = __shfl_xor(s_[r], off);
            const float M  = fmaxf(m_[r], om);
            const float s1 = __expf(m_[r] - M);
            const float s2 = __expf(om - M);
            p_[r] = p_[r] * s1 + op * s2;
            s_[r] = s_[r] * s1 + os * s2;
            m_[r] = M;
        }
    }
    if (tx == 0) {
        #pragma unroll
        for (int r = 0; r < 4; ++r)
            partial[(size_t)gi[r] * CHUNKS + chunk] = make_float4(m_[r], p_[r], s_[r], 0.0f);
    }
}

// ---------------- kernel C: merge partials, final scalar ---------------------
__global__ void finalize_kernel(const float4* __restrict__ partial,
                                const float* __restrict__ w,
                                const float* __restrict__ bce,
                                float* __restrict__ out) {
    const int tid = threadIdx.x;
    float loss_s = 0.0f, bce_s = 0.0f;
    int nval = 0;
    for (int row = tid; row < NROWS; row += 256) {
        float m = -1e30f, p = 0.0f, s = 0.0f;
        #pragma unroll
        for (int k = 0; k < CHUNKS; ++k) {
            const float4 q = partial[(size_t)row * CHUNKS + k];
            const float M  = fmaxf(m, q.x);
            const float s1 = __expf(m - M);
            const float s2 = __expf(q.x - M);
            p = p * s1 + q.y * s2;
            s = s * s1 + q.z * s2;
            m = M;
        }
        if (p > 0.0f) {
            nval += 1;
            loss_s += -logf(p / (s + 1e-8f)) * w[row];
        }
        bce_s += bce[row];
    }
    __shared__ float rl[256], rb[256];
    __shared__ int rn[256];
    rl[tid] = loss_s; rb[tid] = bce_s; rn[tid] = nval;
    __syncthreads();
    for (int off = 128; off; off >>= 1) {
        if (tid < off) { rl[tid] += rl[tid + off]; rb[tid] += rb[tid + off]; rn[tid] += rn[tid + off]; }
        __syncthreads();
    }
    if (tid == 0) {
        const float contrast = (rn[0] > 0) ? rl[0] / (float)rn[0] : 0.0f;
        out[0] = rb[0] / (float)(NROWS * NCLS) + contrast;
    }
}

extern "C" void kernel_launch(void* const* d_in, const int* in_sizes, int n_in,
                              void* d_out, int out_size, void* d_ws, size_t ws_size,
                              hipStream_t stream) {
    const float* emb    = (const float*)d_in[0];
    const float* logits = (const float*)d_in[1];
    const int*   labels = (const int*)d_in[2];
    float* out = (float*)d_out;

    uint8_t* ws = (uint8_t*)d_ws;
    uint64_t* mask  = (uint64_t*)(ws);            // 4096 * 8  = 32 KB
    float*    wrow  = (float*)(ws + 32768);       // 4096 * 4  = 16 KB
    float*    bcerow= (float*)(ws + 49152);       // 4096 * 4  = 16 KB
    float4*   part  = (float4*)(ws + 65536);      // 4096 * 16 * 16 = 1 MB

    prep_kernel<<<NROWS / 4, 256, 0, stream>>>(logits, labels, mask, wrow, bcerow);
    dim3 gridB(CHUNKS, NROWS / BM);
    sim_kernel<<<gridB, 256, 0, stream>>>(emb, mask, part);
    finalize_kernel<<<1, 256, 0, stream>>>(part, wrow, bcerow, out);
}

// Round 2
// 136.160 us; speedup vs baseline: 5.2618x; 5.2618x over previous
//
#include <hip/hip_runtime.h>
#include <hip/hip_bf16.h>
#include <stdint.h>

#define NROWS 4096
#define DIM   1024
#define NCLS  64
#define NTB   32            // 4096/128 tile-blocks per axis
#define NTRI  528           // 32*33/2 upper-triangle tiles
#define NCHUNK 64           // 64-col partial chunks per row

constexpr float TEMP_INV = 1.0f / 0.07f;

typedef __attribute__((ext_vector_type(8))) short  bf16x8;
typedef __attribute__((ext_vector_type(4))) float  f32x4;

__device__ inline void gload_lds16(const void* g, void* l) {
    __builtin_amdgcn_global_load_lds(
        (const __attribute__((address_space(1))) void*)g,
        (__attribute__((address_space(3))) void*)l, 16, 0, 0);
}

// ---------------- kernel A: bce row-sums, entropy weights, label bitmasks ----
__global__ void prep_kernel(const float* __restrict__ logits,
                            const int* __restrict__ labels,
                            uint64_t* __restrict__ maskout,
                            float* __restrict__ wout,
                            float* __restrict__ bceout) {
    const int row  = blockIdx.x * 4 + (threadIdx.x >> 6);
    const int lane = threadIdx.x & 63;
    const float l = logits[row * NCLS + lane];
    const int   y = labels[row * NCLS + lane];
    const float yf = (float)y;

    float bce = fmaxf(l, 0.0f) - l * yf + log1pf(expf(-fabsf(l)));
    const float pr = 1.0f / (1.0f + expf(-l));
    const float ent = -(pr * logf(pr + 1e-8f) + (1.0f - pr) * logf(1.0f - pr + 1e-8f));
    float entw = ent * yf;
    float ycnt = yf;

    #pragma unroll
    for (int off = 32; off; off >>= 1) {
        bce  += __shfl_down(bce, off);
        entw += __shfl_down(entw, off);
        ycnt += __shfl_down(ycnt, off);
    }
    const uint64_t m = __ballot(y != 0);
    if (lane == 0) {
        maskout[row] = m;
        wout[row]    = entw / (ycnt + 1e-8f);
        bceout[row]  = bce;
    }
}

// ---------------- kernel B: fp32 -> bf16 copy, PRE-SWIZZLED (slot ^= row&7) --
// swizzle granule: 16B slots (8 bf16) within each 64-element K-block (128B)
__global__ void convert_kernel(const float* __restrict__ emb,
                               __hip_bfloat16* __restrict__ out) {
    const int t   = blockIdx.x * 256 + threadIdx.x;   // one 8-elem slot each
    const int row = t >> 7;                           // 128 slots per row
    const int sl  = t & 127;
    const int kb  = sl >> 3;
    const int s   = sl & 7;
    const float* src = emb + (size_t)row * DIM + kb * 64 + s * 8;
    const float4 a = *(const float4*)src;
    const float4 b = *(const float4*)(src + 4);
    const int sd = s ^ (row & 7);
    union { __hip_bfloat16 h[8]; float4 v; } u;
    u.h[0] = __float2bfloat16(a.x); u.h[1] = __float2bfloat16(a.y);
    u.h[2] = __float2bfloat16(a.z); u.h[3] = __float2bfloat16(a.w);
    u.h[4] = __float2bfloat16(b.x); u.h[5] = __float2bfloat16(b.y);
    u.h[6] = __float2bfloat16(b.z); u.h[7] = __float2bfloat16(b.w);
    *(float4*)(out + (size_t)row * DIM + kb * 64 + sd * 8) = u.v;
}

// ---------------- kernel C: MFMA sim tiles (upper triangle), two epilogues ---
__device__ inline bf16x8 frag_read(const unsigned char* tile, int row, int ks, int lane) {
    const int slot = (ks * 4 + (lane >> 4)) ^ (row & 7);
    return *(const bf16x8*)(tile + row * 128 + slot * 16);
}

__global__ __launch_bounds__(256)
void sim_kernel(const __hip_bfloat16* __restrict__ embb,
                const uint64_t* __restrict__ mask,
                float4* __restrict__ partial) {
    __shared__ __align__(16) unsigned char As[16384];   // [128 rows][64 bf16] swizzled
    __shared__ __align__(16) unsigned char Bs[16384];
    __shared__ uint64_t rmaskS[128];
    __shared__ uint64_t cmaskS[128];

    // linear block id -> upper-triangle (by, bx), by <= bx
    int t = blockIdx.x, by = 0;
    while (t >= NTB - by) { t -= NTB - by; ++by; }
    const int bx = by + t;

    const int tid  = threadIdx.x;
    const int lane = tid & 63;
    const int wid  = tid >> 6;
    const int wm   = wid >> 1;          // wave row-half
    const int wn   = wid & 1;           // wave col-half

    if (tid < 128)      rmaskS[tid]       = mask[by * 128 + tid];
    else                cmaskS[tid - 128] = mask[bx * 128 + (tid - 128)];

    f32x4 acc[4][4];
    #pragma unroll
    for (int i = 0; i < 4; ++i)
        #pragma unroll
        for (int j = 0; j < 4; ++j) acc[i][j] = (f32x4)0.0f;

    const size_t arow0 = (size_t)by * 128;
    const size_t brow0 = (size_t)bx * 128;
    const int lr  = tid >> 3;          // staging row 0..31
    const int lce = (tid & 7) * 8;     // staging col (elements)

    for (int kb = 0; kb < DIM / 64; ++kb) {
        __syncthreads();               // LDS safe to overwrite
        #pragma unroll
        for (int is = 0; is < 4; ++is) {
            const int r = is * 32 + lr;
            gload_lds16(embb + (arow0 + r) * DIM + kb * 64 + lce, As + is * 4096 + tid * 16);
            gload_lds16(embb + (brow0 + r) * DIM + kb * 64 + lce, Bs + is * 4096 + tid * 16);
        }
        asm volatile("s_waitcnt vmcnt(0)" ::: "memory");
        __syncthreads();

        #pragma unroll
        for (int ks = 0; ks < 2; ++ks) {
            bf16x8 af[4], bfr[4];
            #pragma unroll
            for (int f = 0; f < 4; ++f) {
                af[f]  = frag_read(As, wm * 64 + f * 16 + (lane & 15), ks, lane);
                bfr[f] = frag_read(Bs, wn * 64 + f * 16 + (lane & 15), ks, lane);
            }
            #pragma unroll
            for (int i = 0; i < 4; ++i)
                #pragma unroll
                for (int j = 0; j < 4; ++j)
                    acc[i][j] = __builtin_amdgcn_mfma_f32_16x16x32_bf16(af[i], bfr[j], acc[i][j], 0, 0, 0);
        }
    }

    // C/D layout: col = lane&15, row = (lane>>4)*4 + reg   [m89-verified]
    const int lg = lane >> 4;
    const int lc = lane & 15;

    uint64_t cmR[4];
    #pragma unroll
    for (int nf = 0; nf < 4; ++nf) cmR[nf] = cmaskS[wn * 64 + nf * 16 + lc];

    // ---- row epilogue: per-row (m,p,s) over this tile's 128 cols (per wave: 64) ----
    #pragma unroll
    for (int mf = 0; mf < 4; ++mf) {
        #pragma unroll
        for (int rg = 0; rg < 4; ++rg) {
            const int r    = wm * 64 + mf * 16 + lg * 4 + rg;
            const int grow = by * 128 + r;
            const uint64_t rm = rmaskS[r];
            float v[4]; bool od[4], pp[4];
            float mx = -1e30f;
            #pragma unroll
            for (int nf = 0; nf < 4; ++nf) {
                const int gcol = bx * 128 + wn * 64 + nf * 16 + lc;
                v[nf]  = acc[mf][nf][rg] * TEMP_INV;
                od[nf] = (gcol != grow);
                pp[nf] = od[nf] && ((rm & cmR[nf]) != 0ull);
                if (od[nf]) mx = fmaxf(mx, v[nf]);
            }
            #pragma unroll
            for (int o = 1; o < 16; o <<= 1) mx = fmaxf(mx, __shfl_xor(mx, o));
            float sp = 0.0f, ss = 0.0f;
            #pragma unroll
            for (int nf = 0; nf < 4; ++nf) {
                if (od[nf]) {
                    const float e = __expf(v[nf] - mx);
                    ss += e;
                    if (pp[nf]) sp += e;
                }
            }
            #pragma unroll
            for (int o = 1; o < 16; o <<= 1) { sp += __shfl_xor(sp, o); ss += __shfl_xor(ss, o); }
            if (lc == 0)
                partial[(size_t)grow * NCHUNK + bx * 2 + wn] = make_float4(mx, sp, ss, 0.0f);
        }
    }

    // ---- col epilogue (symmetric write), skip on diagonal tiles ----
    if (bx != by) {
        #pragma unroll
        for (int nf = 0; nf < 4; ++nf) {
            const int gcol = bx * 128 + wn * 64 + nf * 16 + lc;
            const uint64_t cm = cmR[nf];
            float v[16]; bool pp[16];
            float mx = -1e30f;
            #pragma unroll
            for (int mf = 0; mf < 4; ++mf)
                #pragma unroll
                for (int rg = 0; rg < 4; ++rg) {
                    const int idx = mf * 4 + rg;
                    v[idx] = acc[mf][nf][rg] * TEMP_INV;     // rows != cols here, all od
                    pp[idx] = ((rmaskS[wm * 64 + mf * 16 + lg * 4 + rg] & cm) != 0ull);
                    mx = fmaxf(mx, v[idx]);
                }
            mx = fmaxf(mx, __shfl_xor(mx, 16));
            mx = fmaxf(mx, __shfl_xor(mx, 32));
            float sp = 0.0f, ss = 0.0f;
            #pragma unroll
            for (int idx = 0; idx < 16; ++idx) {
                const float e = __expf(v[idx] - mx);
                ss += e;
                if (pp[idx]) sp += e;
            }
            sp += __shfl_xor(sp, 16); sp += __shfl_xor(sp, 32);
            ss += __shfl_xor(ss, 16); ss += __shfl_xor(ss, 32);
            if (lane < 16)
                partial[(size_t)gcol * NCHUNK + by * 2 + wm] = make_float4(mx, sp, ss, 0.0f);
        }
    }
}

// ---------------- kernel D: per-row merge of 64 chunks -> block partials -----
__global__ void merge_kernel(const float4* __restrict__ partial,
                             const float* __restrict__ w,
                             const float* __restrict__ bce,
                             float4* __restrict__ bp) {
    const int tid = threadIdx.x;
    const int row = blockIdx.x * 256 + tid;
    float m = -1e30f, p = 0.0f, s = 0.0f;
    #pragma unroll 8
    for (int c = 0; c < NCHUNK; ++c) {
        const float4 q = partial[(size_t)row * NCHUNK + c];
        const float M  = fmaxf(m, q.x);
        const float e1 = __expf(m - M);
        const float e2 = __expf(q.x - M);
        p = p * e1 + q.y * e2;
        s = s * e1 + q.z * e2;
        m = M;
    }
    float li = 0.0f, va = 0.0f;
    if (p > 0.0f) { va = 1.0f; li = -logf(p / (s + 1e-8f)) * w[row]; }
    float b = bce[row];

    __shared__ float rl[256], rv[256], rb[256];
    rl[tid] = li; rv[tid] = va; rb[tid] = b;
    __syncthreads();
    for (int off = 128; off; off >>= 1) {
        if (tid < off) { rl[tid] += rl[tid + off]; rv[tid] += rv[tid + off]; rb[tid] += rb[tid + off]; }
        __syncthreads();
    }
    if (tid == 0) bp[blockIdx.x] = make_float4(rl[0], rv[0], rb[0], 0.0f);
}

// ---------------- kernel E: final scalar ------------------------------------
__global__ void final_kernel(const float4* __restrict__ bp, float* __restrict__ out) {
    const int l = threadIdx.x;
    float li = 0.0f, va = 0.0f, b = 0.0f;
    if (l < 16) { const float4 q = bp[l]; li = q.x; va = q.y; b = q.z; }
    #pragma unroll
    for (int o = 1; o < 16; o <<= 1) {
        li += __shfl_xor(li, o); va += __shfl_xor(va, o); b += __shfl_xor(b, o);
    }
    if (l == 0) {
        const float contrast = (va > 0.0f) ? li / va : 0.0f;
        out[0] = b / (float)(NROWS * NCLS) + contrast;
    }
}

extern "C" void kernel_launch(void* const* d_in, const int* in_sizes, int n_in,
                              void* d_out, int out_size, void* d_ws, size_t ws_size,
                              hipStream_t stream) {
    const float* emb    = (const float*)d_in[0];
    const float* logits = (const float*)d_in[1];
    const int*   labels = (const int*)d_in[2];
    float* out = (float*)d_out;

    uint8_t* ws = (uint8_t*)d_ws;
    uint64_t*       mask  = (uint64_t*)(ws);                    // 32 KB
    float*          wrow  = (float*)(ws + 0x8000);              // 16 KB
    float*          bcer  = (float*)(ws + 0xC000);              // 16 KB
    float4*         bp    = (float4*)(ws + 0x10000);            // 256 B
    float4*         part  = (float4*)(ws + 0x20000);            // 4 MB
    __hip_bfloat16* embb  = (__hip_bfloat16*)(ws + 0x420000);   // 8 MB

    prep_kernel<<<NROWS / 4, 256, 0, stream>>>(logits, labels, mask, wrow, bcer);
    convert_kernel<<<(NROWS * DIM / 8) / 256, 256, 0, stream>>>(emb, embb);
    sim_kernel<<<NTRI, 256, 0, stream>>>(embb, mask, part);
    merge_kernel<<<NROWS / 256, 256, 0, stream>>>(part, wrow, bcer, bp);
    final_kernel<<<1, 64, 0, stream>>>(bp, out);
}

// Round 3
// 126.888 us; speedup vs baseline: 5.6463x; 1.0731x over previous
//
#include <hip/hip_runtime.h>
#include <hip/hip_bf16.h>
#include <stdint.h>

#define NROWS 4096
#define DIM   1024
#define NCLS  64
#define NTB   32            // 4096/128 tile-blocks per axis
#define NTRI  528           // 32*33/2 upper-triangle tiles
#define NCHUNK 64           // 64-col partial chunks per row

constexpr float TEMP_INV = 1.0f / 0.07f;

typedef __attribute__((ext_vector_type(8))) short  bf16x8;
typedef __attribute__((ext_vector_type(4))) float  f32x4;

__device__ inline void gload_lds16(const void* g, void* l) {
    __builtin_amdgcn_global_load_lds(
        (const __attribute__((address_space(1))) void*)g,
        (__attribute__((address_space(3))) void*)l, 16, 0, 0);
}

// ---------------- kernel A: bce row-sums, entropy weights, label bitmasks ----
__global__ void prep_kernel(const float* __restrict__ logits,
                            const int* __restrict__ labels,
                            uint64_t* __restrict__ maskout,
                            float* __restrict__ wout,
                            float* __restrict__ bceout) {
    const int row  = blockIdx.x * 4 + (threadIdx.x >> 6);
    const int lane = threadIdx.x & 63;
    const float l = logits[row * NCLS + lane];
    const int   y = labels[row * NCLS + lane];
    const float yf = (float)y;

    float bce = fmaxf(l, 0.0f) - l * yf + log1pf(expf(-fabsf(l)));
    const float pr = 1.0f / (1.0f + expf(-l));
    const float ent = -(pr * logf(pr + 1e-8f) + (1.0f - pr) * logf(1.0f - pr + 1e-8f));
    float entw = ent * yf;
    float ycnt = yf;

    #pragma unroll
    for (int off = 32; off; off >>= 1) {
        bce  += __shfl_down(bce, off);
        entw += __shfl_down(entw, off);
        ycnt += __shfl_down(ycnt, off);
    }
    const uint64_t m = __ballot(y != 0);
    if (lane == 0) {
        maskout[row] = m;
        wout[row]    = entw / (ycnt + 1e-8f);
        bceout[row]  = bce;
    }
}

// ---------------- kernel B: fp32 -> bf16 copy, PRE-SWIZZLED (slot ^= row&7) --
__global__ void convert_kernel(const float* __restrict__ emb,
                               __hip_bfloat16* __restrict__ out) {
    const int t   = blockIdx.x * 256 + threadIdx.x;   // one 8-elem slot each
    const int row = t >> 7;                           // 128 slots per row
    const int sl  = t & 127;
    const int kb  = sl >> 3;
    const int s   = sl & 7;
    const float* src = emb + (size_t)row * DIM + kb * 64 + s * 8;
    const float4 a = *(const float4*)src;
    const float4 b = *(const float4*)(src + 4);
    const int sd = s ^ (row & 7);
    union { __hip_bfloat16 h[8]; float4 v; } u;
    u.h[0] = __float2bfloat16(a.x); u.h[1] = __float2bfloat16(a.y);
    u.h[2] = __float2bfloat16(a.z); u.h[3] = __float2bfloat16(a.w);
    u.h[4] = __float2bfloat16(b.x); u.h[5] = __float2bfloat16(b.y);
    u.h[6] = __float2bfloat16(b.z); u.h[7] = __float2bfloat16(b.w);
    *(float4*)(out + (size_t)row * DIM + kb * 64 + sd * 8) = u.v;
}

// ---------------- kernel C: MFMA sim tiles, double-buffered 2-phase ----------
__device__ inline bf16x8 frag_read(const unsigned char* tile, int row, int ks, int lane) {
    const int slot = (ks * 4 + (lane >> 4)) ^ (row & 7);
    return *(const bf16x8*)(tile + row * 128 + slot * 16);
}

__device__ inline void stage_tile(const __hip_bfloat16* __restrict__ embb,
                                  size_t arow0, size_t brow0, int kb,
                                  unsigned char* As, unsigned char* Bs, int tid) {
    const int lr  = tid >> 3;          // staging row 0..31
    const int lce = (tid & 7) * 8;     // staging col (elements)
    #pragma unroll
    for (int is = 0; is < 4; ++is) {
        const int r = is * 32 + lr;
        gload_lds16(embb + (arow0 + r) * DIM + kb * 64 + lce, As + is * 4096 + tid * 16);
        gload_lds16(embb + (brow0 + r) * DIM + kb * 64 + lce, Bs + is * 4096 + tid * 16);
    }
}

__device__ inline void compute_tile(const unsigned char* As, const unsigned char* Bs,
                                    int wm, int wn, int lane, f32x4 acc[4][4]) {
    #pragma unroll
    for (int ks = 0; ks < 2; ++ks) {
        bf16x8 af[4], bfr[4];
        #pragma unroll
        for (int f = 0; f < 4; ++f) {
            af[f]  = frag_read(As, wm * 64 + f * 16 + (lane & 15), ks, lane);
            bfr[f] = frag_read(Bs, wn * 64 + f * 16 + (lane & 15), ks, lane);
        }
        #pragma unroll
        for (int i = 0; i < 4; ++i)
            #pragma unroll
            for (int j = 0; j < 4; ++j)
                acc[i][j] = __builtin_amdgcn_mfma_f32_16x16x32_bf16(af[i], bfr[j], acc[i][j], 0, 0, 0);
    }
}

__global__ __launch_bounds__(256)
void sim_kernel(const __hip_bfloat16* __restrict__ embb,
                const uint64_t* __restrict__ mask,
                float4* __restrict__ partial) {
    __shared__ __align__(16) unsigned char A0[16384];   // [128 rows][64 bf16] swizzled
    __shared__ __align__(16) unsigned char B0[16384];
    __shared__ __align__(16) unsigned char A1[16384];
    __shared__ __align__(16) unsigned char B1[16384];
    __shared__ uint64_t rmaskS[128];
    __shared__ uint64_t cmaskS[128];

    // linear block id -> upper-triangle (by, bx), by <= bx
    int t = blockIdx.x, by = 0;
    while (t >= NTB - by) { t -= NTB - by; ++by; }
    const int bx = by + t;

    const int tid  = threadIdx.x;
    const int lane = tid & 63;
    const int wid  = tid >> 6;
    const int wm   = wid >> 1;          // wave row-half
    const int wn   = wid & 1;           // wave col-half

    if (tid < 128)      rmaskS[tid]       = mask[by * 128 + tid];
    else                cmaskS[tid - 128] = mask[bx * 128 + (tid - 128)];

    f32x4 acc[4][4];
    #pragma unroll
    for (int i = 0; i < 4; ++i)
        #pragma unroll
        for (int j = 0; j < 4; ++j) acc[i][j] = (f32x4)0.0f;

    const size_t arow0 = (size_t)by * 128;
    const size_t brow0 = (size_t)bx * 128;

    // ---- prologue: stage kb=0 into buf0 ----
    stage_tile(embb, arow0, brow0, 0, A0, B0, tid);
    asm volatile("s_waitcnt vmcnt(0)" ::: "memory");
    __syncthreads();

    // ---- 2-phase pipelined K-loop: 16 K-tiles as 8 double-iterations ----
    #pragma unroll 1
    for (int kb2 = 0; kb2 < 8; ++kb2) {
        // phase A: prefetch kb2*2+1 -> buf1 while computing buf0
        stage_tile(embb, arow0, brow0, kb2 * 2 + 1, A1, B1, tid);
        compute_tile(A0, B0, wm, wn, lane, acc);
        asm volatile("s_waitcnt vmcnt(0)" ::: "memory");
        __syncthreads();
        // phase B: prefetch kb2*2+2 -> buf0 while computing buf1
        if (kb2 < 7) stage_tile(embb, arow0, brow0, kb2 * 2 + 2, A0, B0, tid);
        compute_tile(A1, B1, wm, wn, lane, acc);
        asm volatile("s_waitcnt vmcnt(0)" ::: "memory");
        __syncthreads();
    }

    // C/D layout: col = lane&15, row = (lane>>4)*4 + reg   [m89-verified]
    const int lg = lane >> 4;
    const int lc = lane & 15;

    uint64_t cmR[4];
    #pragma unroll
    for (int nf = 0; nf < 4; ++nf) cmR[nf] = cmaskS[wn * 64 + nf * 16 + lc];

    // ---- row epilogue: per-row (m,p,s) over this tile's cols (per wave: 64) ----
    #pragma unroll
    for (int mf = 0; mf < 4; ++mf) {
        #pragma unroll
        for (int rg = 0; rg < 4; ++rg) {
            const int r    = wm * 64 + mf * 16 + lg * 4 + rg;
            const int grow = by * 128 + r;
            const uint64_t rm = rmaskS[r];
            float v[4]; bool od[4], pp[4];
            float mx = -1e30f;
            #pragma unroll
            for (int nf = 0; nf < 4; ++nf) {
                const int gcol = bx * 128 + wn * 64 + nf * 16 + lc;
                v[nf]  = acc[mf][nf][rg] * TEMP_INV;
                od[nf] = (gcol != grow);
                pp[nf] = od[nf] && ((rm & cmR[nf]) != 0ull);
                if (od[nf]) mx = fmaxf(mx, v[nf]);
            }
            #pragma unroll
            for (int o = 1; o < 16; o <<= 1) mx = fmaxf(mx, __shfl_xor(mx, o));
            float sp = 0.0f, ss = 0.0f;
            #pragma unroll
            for (int nf = 0; nf < 4; ++nf) {
                if (od[nf]) {
                    const float e = __expf(v[nf] - mx);
                    ss += e;
                    if (pp[nf]) sp += e;
                }
            }
            #pragma unroll
            for (int o = 1; o < 16; o <<= 1) { sp += __shfl_xor(sp, o); ss += __shfl_xor(ss, o); }
            if (lc == 0)
                partial[(size_t)grow * NCHUNK + bx * 2 + wn] = make_float4(mx, sp, ss, 0.0f);
        }
    }

    // ---- col epilogue (symmetric write), skip on diagonal tiles ----
    if (bx != by) {
        #pragma unroll
        for (int nf = 0; nf < 4; ++nf) {
            const int gcol = bx * 128 + wn * 64 + nf * 16 + lc;
            const uint64_t cm = cmR[nf];
            float v[16]; bool pp[16];
            float mx = -1e30f;
            #pragma unroll
            for (int mf = 0; mf < 4; ++mf)
                #pragma unroll
                for (int rg = 0; rg < 4; ++rg) {
                    const int idx = mf * 4 + rg;
                    v[idx] = acc[mf][nf][rg] * TEMP_INV;     // rows != cols here, all od
                    pp[idx] = ((rmaskS[wm * 64 + mf * 16 + lg * 4 + rg] & cm) != 0ull);
                    mx = fmaxf(mx, v[idx]);
                }
            mx = fmaxf(mx, __shfl_xor(mx, 16));
            mx = fmaxf(mx, __shfl_xor(mx, 32));
            float sp = 0.0f, ss = 0.0f;
            #pragma unroll
            for (int idx = 0; idx < 16; ++idx) {
                const float e = __expf(v[idx] - mx);
                ss += e;
                if (pp[idx]) sp += e;
            }
            sp += __shfl_xor(sp, 16); sp += __shfl_xor(sp, 32);
            ss += __shfl_xor(ss, 16); ss += __shfl_xor(ss, 32);
            if (lane < 16)
                partial[(size_t)gcol * NCHUNK + by * 2 + wm] = make_float4(mx, sp, ss, 0.0f);
        }
    }
}

// ---------------- kernel D: per-row merge, one WAVE per row ------------------
__global__ void merge_kernel(const float4* __restrict__ partial,
                             const float* __restrict__ w,
                             const float* __restrict__ bce,
                             float4* __restrict__ bp) {
    const int tid  = threadIdx.x;
    const int lane = tid & 63;
    const int wv   = tid >> 6;
    const int row  = blockIdx.x * 4 + wv;

    const float4 q = partial[(size_t)row * NCHUNK + lane];   // lane == chunk
    float m = q.x, p = q.y, s = q.z;
    #pragma unroll
    for (int o = 1; o < 64; o <<= 1) {
        const float om = __shfl_xor(m, o);
        const float op = __shfl_xor(p, o);
        const float os = __shfl_xor(s, o);
        const float M  = fmaxf(m, om);
        const float e1 = __expf(m - M);
        const float e2 = __expf(om - M);
        p = p * e1 + op * e2;
        s = s * e1 + os * e2;
        m = M;
    }
    __shared__ float rl[4], rv[4], rb[4];
    if (lane == 0) {
        float li = 0.0f, va = 0.0f;
        if (p > 0.0f) { va = 1.0f; li = -logf(p / (s + 1e-8f)) * w[row]; }
        rl[wv] = li; rv[wv] = va; rb[wv] = bce[row];
    }
    __syncthreads();
    if (tid == 0)
        bp[blockIdx.x] = make_float4(rl[0] + rl[1] + rl[2] + rl[3],
                                     rv[0] + rv[1] + rv[2] + rv[3],
                                     rb[0] + rb[1] + rb[2] + rb[3], 0.0f);
}

// ---------------- kernel E: final scalar over 1024 block partials ------------
__global__ void final_kernel(const float4* __restrict__ bp, float* __restrict__ out) {
    const int tid = threadIdx.x;   // 256
    float li = 0.0f, va = 0.0f, b = 0.0f;
    #pragma unroll
    for (int k = 0; k < 4; ++k) {
        const float4 q = bp[k * 256 + tid];
        li += q.x; va += q.y; b += q.z;
    }
    #pragma unroll
    for (int o = 1; o < 64; o <<= 1) {
        li += __shfl_xor(li, o); va += __shfl_xor(va, o); b += __shfl_xor(b, o);
    }
    __shared__ float sl[4], sv[4], sb[4];
    if ((tid & 63) == 0) { sl[tid >> 6] = li; sv[tid >> 6] = va; sb[tid >> 6] = b; }
    __syncthreads();
    if (tid == 0) {
        const float L = sl[0] + sl[1] + sl[2] + sl[3];
        const float V = sv[0] + sv[1] + sv[2] + sv[3];
        const float B = sb[0] + sb[1] + sb[2] + sb[3];
        out[0] = B / (float)(NROWS * NCLS) + (V > 0.0f ? L / V : 0.0f);
    }
}

extern "C" void kernel_launch(void* const* d_in, const int* in_sizes, int n_in,
                              void* d_out, int out_size, void* d_ws, size_t ws_size,
                              hipStream_t stream) {
    const float* emb    = (const float*)d_in[0];
    const float* logits = (const float*)d_in[1];
    const int*   labels = (const int*)d_in[2];
    float* out = (float*)d_out;

    uint8_t* ws = (uint8_t*)d_ws;
    uint64_t*       mask  = (uint64_t*)(ws);                    // 32 KB
    float*          wrow  = (float*)(ws + 0x8000);              // 16 KB
    float*          bcer  = (float*)(ws + 0xC000);              // 16 KB
    float4*         bp    = (float4*)(ws + 0x10000);            // 16 KB
    float4*         part  = (float4*)(ws + 0x20000);            // 4 MB
    __hip_bfloat16* embb  = (__hip_bfloat16*)(ws + 0x420000);   // 8 MB

    prep_kernel<<<NROWS / 4, 256, 0, stream>>>(logits, labels, mask, wrow, bcer);
    convert_kernel<<<(NROWS * DIM / 8) / 256, 256, 0, stream>>>(emb, embb);
    sim_kernel<<<NTRI, 256, 0, stream>>>(embb, mask, part);
    merge_kernel<<<NROWS / 4, 256, 0, stream>>>(part, wrow, bcer, bp);
    final_kernel<<<1, 256, 0, stream>>>(bp, out);
}